// Round 4
// baseline (26328.824 us; speedup 1.0000x reference)
//
#include <hip/hip_runtime.h>
#include <hip/hip_bf16.h>
#include <math.h>

#define BBATCH 256
#define CB 64            // batch chunk (keeps row counts divisible by 64)
#define DMODEL 512
#define NHEAD 4
#define DHEAD 128
#define DFFN 1024
#define KCB 8192

// ---------------- conv weight transform: wc[(k*512+di)*512 + do] = cw[do][di][k]
__global__ __launch_bounds__(256) void k_wconv(const float* __restrict__ cw,
                                               float* __restrict__ wc) {
    int idx = blockIdx.x * 256 + threadIdx.x;
    if (idx >= 3 * DMODEL * DMODEL) return;
    int dout = idx & (DMODEL - 1);
    int rest = idx >> 9;
    int di = rest & (DMODEL - 1);
    int k = rest >> 9;
    wc[idx] = cw[((size_t)dout * DMODEL + di) * 3 + k];
}

// ---------------- conv GEMM with fused frame gather + exact GELU, fp64 accumulate.
// Chunk-local: xin is [CB, Tin, 512]; logical A[m][c] = xin[b, clamp(2t-2+c/512,0), c%512].
__global__ __launch_bounds__(256) void k_gemm_conv(const float* __restrict__ xin,
                                                   const float* __restrict__ Wc,
                                                   const float* __restrict__ bias,
                                                   float* __restrict__ C,
                                                   int Tin, int Tout) {
    __shared__ __align__(16) float As[16][68];
    __shared__ __align__(16) float Bs[16][68];
    int tid = threadIdx.x;
    int tx = tid & 15, ty = tid >> 4;
    int m0 = blockIdx.y * 64, n0 = blockIdx.x * 64;
    double acc[4][4];
#pragma unroll
    for (int i = 0; i < 4; i++)
#pragma unroll
        for (int j = 0; j < 4; j++) acc[i][j] = 0.0;

    for (int k0 = 0; k0 < 3 * DMODEL; k0 += 16) {
#pragma unroll
        for (int i = 0; i < 4; i++) {
            int t = tid + i * 256;
            int kk = t & 15, mm = t >> 4;
            int c = k0 + kk;
            int m = m0 + mm;
            int b = m / Tout;
            int tt = m - b * Tout;
            int f = 2 * tt - 2 + (c >> 9);
            if (f < 0) f = 0;
            As[kk][mm] = xin[((size_t)b * Tin + f) * DMODEL + (c & 511)];
            int nn = t & 63, kb = t >> 6;
            Bs[kb][nn] = Wc[(size_t)(k0 + kb) * DMODEL + n0 + nn];
        }
        __syncthreads();
#pragma unroll
        for (int kk = 0; kk < 16; kk++) {
            float4 af = *(const float4*)&As[kk][ty * 4];
            float4 bf = *(const float4*)&Bs[kk][tx * 4];
            double a[4] = {(double)af.x, (double)af.y, (double)af.z, (double)af.w};
            double b[4] = {(double)bf.x, (double)bf.y, (double)bf.z, (double)bf.w};
#pragma unroll
            for (int i = 0; i < 4; i++)
#pragma unroll
                for (int j = 0; j < 4; j++) acc[i][j] = fma(a[i], b[j], acc[i][j]);
        }
        __syncthreads();
    }
#pragma unroll
    for (int i = 0; i < 4; i++) {
#pragma unroll
        for (int j = 0; j < 4; j++) {
            double v = acc[i][j] + (double)bias[n0 + tx * 4 + j];
            v = 0.5 * v * (1.0 + erf(v * 0.7071067811865476));
            C[(size_t)(m0 + ty * 4 + i) * DMODEL + n0 + tx * 4 + j] = (float)v;
        }
    }
}

// ---------------- generic GEMM, fp64 accumulate. ACT: 0 none, 2 relu
template <int ACT>
__global__ __launch_bounds__(256) void k_gemm(const float* __restrict__ A, int lda,
                                              const float* __restrict__ Bm, int ldb,
                                              const float* __restrict__ bias,
                                              float* __restrict__ C, int ldc,
                                              int M, int N, int K) {
    __shared__ __align__(16) float As[16][68];
    __shared__ __align__(16) float Bs[16][68];
    int tid = threadIdx.x;
    int tx = tid & 15, ty = tid >> 4;
    int m0 = blockIdx.y * 64, n0 = blockIdx.x * 64;
    double acc[4][4];
#pragma unroll
    for (int i = 0; i < 4; i++)
#pragma unroll
        for (int j = 0; j < 4; j++) acc[i][j] = 0.0;

    for (int k0 = 0; k0 < K; k0 += 16) {
#pragma unroll
        for (int i = 0; i < 4; i++) {
            int t = tid + i * 256;
            int kk = t & 15, mm = t >> 4;
            As[kk][mm] = A[(size_t)(m0 + mm) * lda + k0 + kk];
            int nn = t & 63, kb = t >> 6;          // kb spans 0..15 across i
            Bs[kb][nn] = Bm[(size_t)(k0 + kb) * ldb + n0 + nn];
        }
        __syncthreads();
#pragma unroll
        for (int kk = 0; kk < 16; kk++) {
            float4 af = *(const float4*)&As[kk][ty * 4];
            float4 bf = *(const float4*)&Bs[kk][tx * 4];
            double a[4] = {(double)af.x, (double)af.y, (double)af.z, (double)af.w};
            double b[4] = {(double)bf.x, (double)bf.y, (double)bf.z, (double)bf.w};
#pragma unroll
            for (int i = 0; i < 4; i++)
#pragma unroll
                for (int j = 0; j < 4; j++) acc[i][j] = fma(a[i], b[j], acc[i][j]);
        }
        __syncthreads();
    }
#pragma unroll
    for (int i = 0; i < 4; i++) {
#pragma unroll
        for (int j = 0; j < 4; j++) {
            double v = acc[i][j] + (double)bias[n0 + tx * 4 + j];
            if (ACT == 2) v = v > 0.0 ? v : 0.0;
            C[(size_t)(m0 + ty * 4 + i) * ldc + n0 + tx * 4 + j] = (float)v;
        }
    }
}

// ---------------- attention, separate q,k,v buffers [Mc,512]; out may alias q
// (block (i,h,b) is the sole reader AND sole writer of q's (b,i,h)-slice,
//  and reads it before writing — in-place is safe; no __restrict__ on q/out)
__global__ __launch_bounds__(128) void k_attn3(const float* q,
                                               const float* __restrict__ k,
                                               const float* __restrict__ v,
                                               float* out, int T) {
    int i = blockIdx.x, h = blockIdx.y, b = blockIdx.z;
    int tid = threadIdx.x;
    __shared__ float qs[DHEAD];
    __shared__ double sc[128];
    __shared__ double red[2];
    size_t rowbase = (size_t)b * T;
    qs[tid] = q[(rowbase + i) * DMODEL + h * DHEAD + tid];
    __syncthreads();
    double sv = -1e300;
    if (tid <= i && tid < T) {
        const float* kr = k + (rowbase + tid) * DMODEL + h * DHEAD;
        double s = 0.0;
#pragma unroll 8
        for (int d = 0; d < DHEAD; d++) s = fma((double)qs[d], (double)kr[d], s);
        sv = s * 0.08838834764831845;  // 1/sqrt(128)
    }
    sc[tid] = sv;
    __syncthreads();
    if (tid == 0) {
        double m = -1e300;
        for (int j = 0; j <= i; j++) m = sc[j] > m ? sc[j] : m;
        red[0] = m;
    }
    __syncthreads();
    double m = red[0];
    if (tid <= i) sc[tid] = exp(sc[tid] - m);
    __syncthreads();
    if (tid == 0) {
        double s = 0.0;
        for (int j = 0; j <= i; j++) s += sc[j];
        red[1] = s;
    }
    __syncthreads();
    double inv = 1.0 / red[1];
    const float* vb = v + rowbase * DMODEL + h * DHEAD + tid;
    double o = 0.0;
    for (int j = 0; j <= i; j++) o = fma(sc[j], (double)vb[(size_t)j * DMODEL], o);
    out[(rowbase + i) * DMODEL + h * DHEAD + tid] = (float)(o * inv);
}

// ---------------- fused residual-add + LayerNorm, one block per row
__global__ __launch_bounds__(128) void k_ln(const float* __restrict__ resid,
                                            const float* __restrict__ y,
                                            const float* __restrict__ g,
                                            const float* __restrict__ bta,
                                            float* __restrict__ out) {
    int row = blockIdx.x;
    int tid = threadIdx.x;
    size_t off = (size_t)row * DMODEL;
    double t[4];
#pragma unroll
    for (int i = 0; i < 4; i++) {
        int d = tid + i * 128;
        t[i] = (double)resid[off + d] + (double)y[off + d];
    }
    __shared__ double rd[2];
    double s = t[0] + t[1] + t[2] + t[3];
#pragma unroll
    for (int o = 32; o > 0; o >>= 1) s += __shfl_down(s, o, 64);
    if ((tid & 63) == 0) rd[tid >> 6] = s;
    __syncthreads();
    double mean = (rd[0] + rd[1]) * (1.0 / 512.0);
    double vs = 0.0;
#pragma unroll
    for (int i = 0; i < 4; i++) { double dl = t[i] - mean; vs += dl * dl; }
    __syncthreads();
#pragma unroll
    for (int o = 32; o > 0; o >>= 1) vs += __shfl_down(vs, o, 64);
    if ((tid & 63) == 0) rd[tid >> 6] = vs;
    __syncthreads();
    double var = (rd[0] + rd[1]) * (1.0 / 512.0);
    double scale = 1.0 / sqrt(var + 1e-5);
#pragma unroll
    for (int i = 0; i < 4; i++) {
        int d = tid + i * 128;
        out[off + d] = (float)((t[i] - mean) * scale * (double)g[d] + (double)bta[d]);
    }
}

// ---------------- codebook squared norms
__global__ __launch_bounds__(64) void k_cbn(const float* __restrict__ cb,
                                            double* __restrict__ cbn) {
    int row = blockIdx.x;
    int tid = threadIdx.x;
    const float* r = cb + (size_t)row * DMODEL;
    double s = 0.0;
    for (int d = tid; d < DMODEL; d += 64) { double v = (double)r[d]; s = fma(v, v, s); }
#pragma unroll
    for (int o = 32; o > 0; o >>= 1) s += __shfl_down(s, o, 64);
    if (tid == 0) cbn[row] = s;
}

// ---------------- VQ argmin + FLOAT32 output write. 14 rows/block, 16-code tiles.
// d_out is float32: quant values are cb rows, idx written as (float)index.
__global__ __launch_bounds__(256) void k_quant(const float* __restrict__ x,
                                               const float* __restrict__ cb,
                                               const double* __restrict__ cbn,
                                               float* __restrict__ outq,
                                               float* __restrict__ outi) {
    const int R = 14, CT = 16;
    __shared__ double rdd[R][16];
    __shared__ double xn[R];
    __shared__ float xs[R][513];
    __shared__ float cs[CT][513];
    __shared__ int rdi[R][16];
    __shared__ int chosen[R];
    int tid = threadIdx.x;
    int row0 = blockIdx.x * R;

    for (int i = tid; i < R * 512; i += 256) {
        int r = i >> 9, d = i & 511;
        xs[r][d] = x[(size_t)(row0 + r) * DMODEL + d];
    }
    __syncthreads();
    if (tid < R) {
        double s = 0.0;
        for (int d = 0; d < 512; d++) { double v = (double)xs[tid][d]; s = fma(v, v, s); }
        xn[tid] = s;
    }
    __syncthreads();

    int cg = tid & 15;   // code lane within tile
    int rq = tid >> 4;   // row (0..13 active)
    double bd = 1e300; int bi = 0;
    for (int c0 = 0; c0 < KCB; c0 += CT) {
        for (int i = tid; i < CT * 512; i += 256) {
            int r = i >> 9, d = i & 511;
            cs[r][d] = cb[(size_t)(c0 + r) * DMODEL + d];
        }
        __syncthreads();
        if (rq < R) {
            double dot = 0.0;
#pragma unroll 8
            for (int d = 0; d < 512; d++)
                dot = fma((double)xs[rq][d], (double)cs[cg][d], dot);
            double dist = xn[rq] - 2.0 * dot + cbn[c0 + cg];
            if (dist < bd) { bd = dist; bi = c0 + cg; }
        }
        __syncthreads();
    }
    if (rq < R) { rdd[rq][cg] = bd; rdi[rq][cg] = bi; }
    __syncthreads();
    if (tid < R) {
        double best = 1e300; int bidx = 0;
        for (int c = 0; c < 16; c++) {
            if (rdd[tid][c] < best) { best = rdd[tid][c]; bidx = rdi[tid][c]; }
        }
        chosen[tid] = bidx;
    }
    __syncthreads();
    for (int i = tid; i < R * 512; i += 256) {
        int r = i >> 9, d = i & 511;
        outq[(size_t)(row0 + r) * DMODEL + d] = cb[(size_t)chosen[r] * DMODEL + d];
    }
    if (tid < R) outi[row0 + tid] = (float)chosen[tid];
}

extern "C" void kernel_launch(void* const* d_in, const int* in_sizes, int n_in,
                              void* d_out, int out_size, void* d_ws, size_t ws_size,
                              hipStream_t stream) {
    const float* motion = (const float*)d_in[0];
    const float* conv_w = (const float*)d_in[1];
    const float* conv_b = (const float*)d_in[2];
    const float* wqkv   = (const float*)d_in[3];
    const float* bqkv   = (const float*)d_in[4];
    const float* wo     = (const float*)d_in[5];
    const float* bo     = (const float*)d_in[6];
    const float* ln1g   = (const float*)d_in[7];
    const float* ln1b   = (const float*)d_in[8];
    const float* ln2g   = (const float*)d_in[9];
    const float* ln2b   = (const float*)d_in[10];
    const float* w1     = (const float*)d_in[11];
    const float* b1     = (const float*)d_in[12];
    const float* w2     = (const float*)d_in[13];
    const float* b2     = (const float*)d_in[14];
    const float* cb     = (const float*)d_in[15];

    // workspace: 4 chunk slots [6272,512] f32 + Wc(2 layers) + cbn = 57,737,216 B (55.1 MiB)
    const size_t SZc = (size_t)(CB * 98) * DMODEL;      // 3,211,264 floats per slot
    float* wsf = (float*)d_ws;
    float*  S0  = wsf + 0 * SZc;
    float*  S1  = wsf + 1 * SZc;
    float*  S2  = wsf + 2 * SZc;
    float*  S3  = wsf + 3 * SZc;
    float*  Wc  = wsf + 4 * SZc;                        // 2 * 3*512*512 floats
    double* cbn = (double*)(Wc + 2 * 3 * DMODEL * DMODEL);

    k_cbn<<<dim3(KCB), dim3(64), 0, stream>>>(cb, cbn);
    k_wconv<<<dim3(3072), dim3(256), 0, stream>>>(conv_w, Wc);
    k_wconv<<<dim3(3072), dim3(256), 0, stream>>>(conv_w + (size_t)3 * DMODEL * DMODEL,
                                                  Wc + (size_t)3 * DMODEL * DMODEL);

    float* outq = (float*)d_out;
    float* outi = outq + (size_t)(BBATCH * 49) * DMODEL;   // 6,422,528 floats

    for (int c = 0; c < BBATCH / CB; c++) {
        const float* xin = motion + (size_t)c * CB * 196 * DMODEL;
        int Tin = 196;
        for (int l = 0; l < 2; l++) {
            int Tout = Tin / 2;            // 98, then 49
            int M = CB * Tout;             // 6272, then 3136
            const float* wq = wqkv + (size_t)l * DMODEL * 3 * DMODEL;
            const float* bq = bqkv + (size_t)l * 3 * DMODEL;
            const float* WcL = Wc + (size_t)l * 3 * DMODEL * DMODEL;

            // conv (fused gather) + GELU: xin -> S0
            k_gemm_conv<<<dim3(DMODEL / 64, M / 64), dim3(256), 0, stream>>>(
                xin, WcL, conv_b + l * DMODEL, S0, Tin, Tout);
            // q,k,v: S0 @ wqkv slices -> S1,S2,S3
            float* qkvdst[3] = {S1, S2, S3};
            for (int s = 0; s < 3; s++) {
                k_gemm<0><<<dim3(DMODEL / 64, M / 64), dim3(256), 0, stream>>>(
                    S0, DMODEL, wq + s * DMODEL, 3 * DMODEL, bq + s * DMODEL,
                    qkvdst[s], DMODEL, M, DMODEL, DMODEL);
            }
            // attention in-place over q: S1,S2,S3 -> S1
            k_attn3<<<dim3(Tout, NHEAD, CB), dim3(128), 0, stream>>>(S1, S2, S3, S1, Tout);
            // proj: S1 @ wo -> S2
            k_gemm<0><<<dim3(DMODEL / 64, M / 64), dim3(256), 0, stream>>>(
                S1, DMODEL, wo + (size_t)l * DMODEL * DMODEL, DMODEL, bo + l * DMODEL,
                S2, DMODEL, M, DMODEL, DMODEL);
            // LN1(S0 + S2) -> S3
            k_ln<<<dim3(M), dim3(128), 0, stream>>>(S0, S2, ln1g + l * DMODEL, ln1b + l * DMODEL, S3);
            // ff1: S3 @ w1, ReLU -> S1 ([M,1024]; spans S1(+S2) which are both dead)
            k_gemm<2><<<dim3(DFFN / 64, M / 64), dim3(256), 0, stream>>>(
                S3, DMODEL, w1 + (size_t)l * DMODEL * DFFN, DFFN, b1 + l * DFFN,
                S1, DFFN, M, DFFN, DMODEL);
            // ff2: S1[M,1024] @ w2 -> S0
            k_gemm<0><<<dim3(DMODEL / 64, M / 64), dim3(256), 0, stream>>>(
                S1, DFFN, w2 + (size_t)l * DFFN * DMODEL, DMODEL, b2 + l * DMODEL,
                S0, DMODEL, M, DMODEL, DFFN);
            // LN2(S3 + S0) -> S1 (next x)
            k_ln<<<dim3(M), dim3(128), 0, stream>>>(S3, S0, ln2g + l * DMODEL, ln2b + l * DMODEL, S1);

            xin = S1;
            Tin = Tout;
        }
        // quantize this chunk's 3136 rows (in S1)
        k_quant<<<dim3((CB * 49) / 14), dim3(256), 0, stream>>>(
            S1, cb, cbn,
            outq + (size_t)c * CB * 49 * DMODEL,
            outi + (size_t)c * CB * 49);
    }
}

// Round 5
// 14422.905 us; speedup vs baseline: 1.8255x; 1.8255x over previous
//
#include <hip/hip_runtime.h>
#include <hip/hip_bf16.h>
#include <math.h>

#define BBATCH 256
#define DMODEL 512
#define NHEAD 4
#define DHEAD 128
#define DFFN 1024
#define KCB 8192
#define VEPS 0.02f

// ---------------- conv weight transform: wc[(k*512+di)*512 + do] = cw[do][di][k]
__global__ __launch_bounds__(256) void k_wconv(const float* __restrict__ cw,
                                               float* __restrict__ wc) {
    int idx = blockIdx.x * 256 + threadIdx.x;
    if (idx >= 3 * DMODEL * DMODEL) return;
    int dout = idx & (DMODEL - 1);
    int rest = idx >> 9;
    int di = rest & (DMODEL - 1);
    int k = rest >> 9;
    wc[idx] = cw[((size_t)dout * DMODEL + di) * 3 + k];
}

// ---------------- conv GEMM with fused frame gather + exact GELU, fp64 accumulate.
// xin is [NB, Tin, 512]; logical A[m][c] = xin[b, clamp(2t-2+c/512,0), c%512], m=b*Tout+t.
__global__ __launch_bounds__(256) void k_gemm_conv(const float* __restrict__ xin,
                                                   const float* __restrict__ Wc,
                                                   const float* __restrict__ bias,
                                                   float* __restrict__ C,
                                                   int Tin, int Tout) {
    __shared__ __align__(16) float As[16][68];
    __shared__ __align__(16) float Bs[16][68];
    int tid = threadIdx.x;
    int tx = tid & 15, ty = tid >> 4;
    int m0 = blockIdx.y * 64, n0 = blockIdx.x * 64;
    double acc[4][4];
#pragma unroll
    for (int i = 0; i < 4; i++)
#pragma unroll
        for (int j = 0; j < 4; j++) acc[i][j] = 0.0;

    for (int k0 = 0; k0 < 3 * DMODEL; k0 += 16) {
#pragma unroll
        for (int i = 0; i < 4; i++) {
            int t = tid + i * 256;
            int kk = t & 15, mm = t >> 4;
            int c = k0 + kk;
            int m = m0 + mm;
            int b = m / Tout;
            int tt = m - b * Tout;
            int f = 2 * tt - 2 + (c >> 9);
            if (f < 0) f = 0;
            As[kk][mm] = xin[((size_t)b * Tin + f) * DMODEL + (c & 511)];
            int nn = t & 63, kb = t >> 6;
            Bs[kb][nn] = Wc[(size_t)(k0 + kb) * DMODEL + n0 + nn];
        }
        __syncthreads();
#pragma unroll
        for (int kk = 0; kk < 16; kk++) {
            float4 af = *(const float4*)&As[kk][ty * 4];
            float4 bf = *(const float4*)&Bs[kk][tx * 4];
            double a[4] = {(double)af.x, (double)af.y, (double)af.z, (double)af.w};
            double b[4] = {(double)bf.x, (double)bf.y, (double)bf.z, (double)bf.w};
#pragma unroll
            for (int i = 0; i < 4; i++)
#pragma unroll
                for (int j = 0; j < 4; j++) acc[i][j] = fma(a[i], b[j], acc[i][j]);
        }
        __syncthreads();
    }
#pragma unroll
    for (int i = 0; i < 4; i++) {
#pragma unroll
        for (int j = 0; j < 4; j++) {
            double v = acc[i][j] + (double)bias[n0 + tx * 4 + j];
            v = 0.5 * v * (1.0 + erf(v * 0.7071067811865476));
            C[(size_t)(m0 + ty * 4 + i) * DMODEL + n0 + tx * 4 + j] = (float)v;
        }
    }
}

// ---------------- generic GEMM, fp64 accumulate. ACT: 0 none, 2 relu
template <int ACT>
__global__ __launch_bounds__(256) void k_gemm(const float* __restrict__ A, int lda,
                                              const float* __restrict__ Bm, int ldb,
                                              const float* __restrict__ bias,
                                              float* __restrict__ C, int ldc,
                                              int M, int N, int K) {
    __shared__ __align__(16) float As[16][68];
    __shared__ __align__(16) float Bs[16][68];
    int tid = threadIdx.x;
    int tx = tid & 15, ty = tid >> 4;
    int m0 = blockIdx.y * 64, n0 = blockIdx.x * 64;
    double acc[4][4];
#pragma unroll
    for (int i = 0; i < 4; i++)
#pragma unroll
        for (int j = 0; j < 4; j++) acc[i][j] = 0.0;

    for (int k0 = 0; k0 < K; k0 += 16) {
#pragma unroll
        for (int i = 0; i < 4; i++) {
            int t = tid + i * 256;
            int kk = t & 15, mm = t >> 4;
            As[kk][mm] = A[(size_t)(m0 + mm) * lda + k0 + kk];
            int nn = t & 63, kb = t >> 6;
            Bs[kb][nn] = Bm[(size_t)(k0 + kb) * ldb + n0 + nn];
        }
        __syncthreads();
#pragma unroll
        for (int kk = 0; kk < 16; kk++) {
            float4 af = *(const float4*)&As[kk][ty * 4];
            float4 bf = *(const float4*)&Bs[kk][tx * 4];
            double a[4] = {(double)af.x, (double)af.y, (double)af.z, (double)af.w};
            double b[4] = {(double)bf.x, (double)bf.y, (double)bf.z, (double)bf.w};
#pragma unroll
            for (int i = 0; i < 4; i++)
#pragma unroll
                for (int j = 0; j < 4; j++) acc[i][j] = fma(a[i], b[j], acc[i][j]);
        }
        __syncthreads();
    }
#pragma unroll
    for (int i = 0; i < 4; i++) {
#pragma unroll
        for (int j = 0; j < 4; j++) {
            double v = acc[i][j] + (double)bias[n0 + tx * 4 + j];
            if (ACT == 2) v = v > 0.0 ? v : 0.0;
            C[(size_t)(m0 + ty * 4 + i) * ldc + n0 + tx * 4 + j] = (float)v;
        }
    }
}

// ---------------- attention, separate q,k,v buffers; out may alias q
__global__ __launch_bounds__(128) void k_attn3(const float* q,
                                               const float* __restrict__ k,
                                               const float* __restrict__ v,
                                               float* out, int T) {
    int i = blockIdx.x, h = blockIdx.y, b = blockIdx.z;
    int tid = threadIdx.x;
    __shared__ float qs[DHEAD];
    __shared__ double sc[128];
    __shared__ double red[2];
    size_t rowbase = (size_t)b * T;
    qs[tid] = q[(rowbase + i) * DMODEL + h * DHEAD + tid];
    __syncthreads();
    double sv = -1e300;
    if (tid <= i && tid < T) {
        const float* kr = k + (rowbase + tid) * DMODEL + h * DHEAD;
        double s = 0.0;
#pragma unroll 8
        for (int d = 0; d < DHEAD; d++) s = fma((double)qs[d], (double)kr[d], s);
        sv = s * 0.08838834764831845;
    }
    sc[tid] = sv;
    __syncthreads();
    if (tid == 0) {
        double m = -1e300;
        for (int j = 0; j <= i; j++) m = sc[j] > m ? sc[j] : m;
        red[0] = m;
    }
    __syncthreads();
    double m = red[0];
    if (tid <= i) sc[tid] = exp(sc[tid] - m);
    __syncthreads();
    if (tid == 0) {
        double s = 0.0;
        for (int j = 0; j <= i; j++) s += sc[j];
        red[1] = s;
    }
    __syncthreads();
    double inv = 1.0 / red[1];
    const float* vb = v + rowbase * DMODEL + h * DHEAD + tid;
    double o = 0.0;
    for (int j = 0; j <= i; j++) o = fma(sc[j], (double)vb[(size_t)j * DMODEL], o);
    out[(rowbase + i) * DMODEL + h * DHEAD + tid] = (float)(o * inv);
}

// ---------------- fused residual-add + LayerNorm, one block per row
__global__ __launch_bounds__(128) void k_ln(const float* __restrict__ resid,
                                            const float* __restrict__ y,
                                            const float* __restrict__ g,
                                            const float* __restrict__ bta,
                                            float* __restrict__ out) {
    int row = blockIdx.x;
    int tid = threadIdx.x;
    size_t off = (size_t)row * DMODEL;
    double t[4];
#pragma unroll
    for (int i = 0; i < 4; i++) {
        int d = tid + i * 128;
        t[i] = (double)resid[off + d] + (double)y[off + d];
    }
    __shared__ double rd[2];
    double s = t[0] + t[1] + t[2] + t[3];
#pragma unroll
    for (int o = 32; o > 0; o >>= 1) s += __shfl_down(s, o, 64);
    if ((tid & 63) == 0) rd[tid >> 6] = s;
    __syncthreads();
    double mean = (rd[0] + rd[1]) * (1.0 / 512.0);
    double vs = 0.0;
#pragma unroll
    for (int i = 0; i < 4; i++) { double dl = t[i] - mean; vs += dl * dl; }
    __syncthreads();
#pragma unroll
    for (int o = 32; o > 0; o >>= 1) vs += __shfl_down(vs, o, 64);
    if ((tid & 63) == 0) rd[tid >> 6] = vs;
    __syncthreads();
    double var = (rd[0] + rd[1]) * (1.0 / 512.0);
    double scale = 1.0 / sqrt(var + 1e-5);
#pragma unroll
    for (int i = 0; i < 4; i++) {
        int d = tid + i * 128;
        out[off + d] = (float)((t[i] - mean) * scale * (double)g[d] + (double)bta[d]);
    }
}

// ---------------- codebook squared norms (fp64)
__global__ __launch_bounds__(64) void k_cbn(const float* __restrict__ cb,
                                            double* __restrict__ cbn) {
    int row = blockIdx.x;
    int tid = threadIdx.x;
    const float* r = cb + (size_t)row * DMODEL;
    double s = 0.0;
    for (int d = tid; d < DMODEL; d += 64) { double v = (double)r[d]; s = fma(v, v, s); }
#pragma unroll
    for (int o = 32; o > 0; o >>= 1) s += __shfl_down(s, o, 64);
    if (tid == 0) cbn[row] = s;
}

// ---------------- VQ phase 1: fp32 distances, per-row global top-2 per code-split.
// Grid (nrows/64, 4). Block: 64 rows x 2048 codes, GEMM-tiled 64x64x16.
// score = cbn[c] - 2*dot (||x||^2 common per row, dropped). cand: (d1,i1,d2,i2).
__global__ __launch_bounds__(256) void k_vq1(const float* __restrict__ x,
                                             const float* __restrict__ cb,
                                             const double* __restrict__ cbn,
                                             float4* __restrict__ cand, int nrows) {
    __shared__ __align__(16) float Xs[16][68];   // [k][row]
    __shared__ float Cs[64][20];                 // [code][k]
    __shared__ float sD[64][16][2];
    __shared__ int   sI[64][16][2];
    int tid = threadIdx.x, tx = tid & 15, ty = tid >> 4;
    int r0 = blockIdx.x * 64;
    int cbase = blockIdx.y * 2048;
    float b1[4], b2[4]; int i1[4], i2[4];
#pragma unroll
    for (int i = 0; i < 4; i++) { b1[i] = 1e30f; b2[i] = 1e30f; i1[i] = 0; i2[i] = 0; }

    for (int c0 = cbase; c0 < cbase + 2048; c0 += 64) {
        float acc[4][4];
#pragma unroll
        for (int i = 0; i < 4; i++)
#pragma unroll
            for (int j = 0; j < 4; j++) acc[i][j] = 0.0f;

        for (int k0 = 0; k0 < DMODEL; k0 += 16) {
#pragma unroll
            for (int i = 0; i < 4; i++) {
                int t = tid + i * 256;
                int kk = t & 15, mm = t >> 4;
                Xs[kk][mm] = x[(size_t)(r0 + mm) * DMODEL + k0 + kk];
                Cs[mm][kk] = cb[(size_t)(c0 + mm) * DMODEL + k0 + kk];
            }
            __syncthreads();
#pragma unroll
            for (int kk = 0; kk < 16; kk++) {
                float4 xa = *(const float4*)&Xs[kk][ty * 4];
                float cv0 = Cs[tx * 4 + 0][kk];
                float cv1 = Cs[tx * 4 + 1][kk];
                float cv2 = Cs[tx * 4 + 2][kk];
                float cv3 = Cs[tx * 4 + 3][kk];
                float xv[4] = {xa.x, xa.y, xa.z, xa.w};
#pragma unroll
                for (int i = 0; i < 4; i++) {
                    acc[i][0] = fmaf(xv[i], cv0, acc[i][0]);
                    acc[i][1] = fmaf(xv[i], cv1, acc[i][1]);
                    acc[i][2] = fmaf(xv[i], cv2, acc[i][2]);
                    acc[i][3] = fmaf(xv[i], cv3, acc[i][3]);
                }
            }
            __syncthreads();
        }
#pragma unroll
        for (int j = 0; j < 4; j++) {
            int ci = c0 + tx * 4 + j;
            float cn = (float)cbn[ci];
#pragma unroll
            for (int i = 0; i < 4; i++) {
                float d = cn - 2.0f * acc[i][j];
                if (d < b1[i]) { b2[i] = b1[i]; i2[i] = i1[i]; b1[i] = d; i1[i] = ci; }
                else if (d < b2[i]) { b2[i] = d; i2[i] = ci; }
            }
        }
    }
#pragma unroll
    for (int i = 0; i < 4; i++) {
        int r = ty * 4 + i;
        sD[r][tx][0] = b1[i]; sD[r][tx][1] = b2[i];
        sI[r][tx][0] = i1[i]; sI[r][tx][1] = i2[i];
    }
    __syncthreads();
    if (tid < 64) {
        float d1 = 1e30f, d2 = 1e30f; int j1 = 0, j2 = 0;
        for (int t = 0; t < 16; t++) {
#pragma unroll
            for (int e = 0; e < 2; e++) {
                float d = sD[tid][t][e]; int ix = sI[tid][t][e];
                if (d < d1 || (d == d1 && ix < j1)) { d2 = d1; j2 = j1; d1 = d; j1 = ix; }
                else if (d < d2 || (d == d2 && ix < j2)) { d2 = d; j2 = ix; }
            }
        }
        cand[(size_t)blockIdx.y * nrows + r0 + tid] =
            make_float4(d1, __int_as_float(j1), d2, __int_as_float(j2));
    }
}

// ---------------- VQ phase 2: merge 4 splits' top-2; flag near-ties for exact rescan
__global__ __launch_bounds__(256) void k_vq2(const float4* __restrict__ cand,
                                             int* __restrict__ idxbuf,
                                             int* __restrict__ flagbuf, int nrows) {
    int row = blockIdx.x * 256 + threadIdx.x;
    if (row >= nrows) return;
    float d1 = 1e30f, d2 = 1e30f; int j1 = 0, j2 = 0;
#pragma unroll
    for (int s = 0; s < 4; s++) {
        float4 c = cand[(size_t)s * nrows + row];
        float dd[2] = {c.x, c.z};
        int ii[2] = {__float_as_int(c.y), __float_as_int(c.w)};
#pragma unroll
        for (int e = 0; e < 2; e++) {
            float d = dd[e]; int ix = ii[e];
            if (d < d1 || (d == d1 && ix < j1)) { d2 = d1; j2 = j1; d1 = d; j1 = ix; }
            else if (d < d2 || (d == d2 && ix < j2)) { d2 = d; j2 = ix; }
        }
    }
    idxbuf[row] = j1;
    flagbuf[row] = (d2 - d1 < VEPS) ? 1 : 0;
}

// ---------------- VQ phase 3: exact fp64 rescan for flagged rows; write outputs
__global__ __launch_bounds__(256) void k_vq3(const float* __restrict__ x,
                                             const float* __restrict__ cb,
                                             const double* __restrict__ cbn,
                                             const int* __restrict__ idxbuf,
                                             const int* __restrict__ flagbuf,
                                             float* __restrict__ outq,
                                             float* __restrict__ outi) {
    int row = blockIdx.x;
    int tid = threadIdx.x;
    int best = idxbuf[row];
    if (flagbuf[row]) {
        __shared__ float xs[DMODEL];
        __shared__ double sd[256];
        __shared__ int si[256];
        xs[tid] = x[(size_t)row * DMODEL + tid];
        xs[tid + 256] = x[(size_t)row * DMODEL + tid + 256];
        __syncthreads();
        double bd = 1e300; int bi = 0x7fffffff;
        for (int c = tid; c < KCB; c += 256) {
            const float* cr = cb + (size_t)c * DMODEL;
            double dot = 0.0;
#pragma unroll 8
            for (int d = 0; d < DMODEL; d++) dot = fma((double)xs[d], (double)cr[d], dot);
            double dist = cbn[c] - 2.0 * dot;
            if (dist < bd || (dist == bd && c < bi)) { bd = dist; bi = c; }
        }
        sd[tid] = bd; si[tid] = bi;
        __syncthreads();
        for (int off = 128; off > 0; off >>= 1) {
            if (tid < off) {
                if (sd[tid + off] < sd[tid] ||
                    (sd[tid + off] == sd[tid] && si[tid + off] < si[tid])) {
                    sd[tid] = sd[tid + off]; si[tid] = si[tid + off];
                }
            }
            __syncthreads();
        }
        best = si[0];
    }
    const float* crow = cb + (size_t)best * DMODEL;
    outq[(size_t)row * DMODEL + tid] = crow[tid];
    outq[(size_t)row * DMODEL + tid + 256] = crow[tid + 256];
    if (tid == 0) outi[row] = (float)best;
}

extern "C" void kernel_launch(void* const* d_in, const int* in_sizes, int n_in,
                              void* d_out, int out_size, void* d_ws, size_t ws_size,
                              hipStream_t stream) {
    const float* motion = (const float*)d_in[0];
    const float* conv_w = (const float*)d_in[1];
    const float* conv_b = (const float*)d_in[2];
    const float* wqkv   = (const float*)d_in[3];
    const float* bqkv   = (const float*)d_in[4];
    const float* wo     = (const float*)d_in[5];
    const float* bo     = (const float*)d_in[6];
    const float* ln1g   = (const float*)d_in[7];
    const float* ln1b   = (const float*)d_in[8];
    const float* ln2g   = (const float*)d_in[9];
    const float* ln2b   = (const float*)d_in[10];
    const float* w1     = (const float*)d_in[11];
    const float* b1     = (const float*)d_in[12];
    const float* w2     = (const float*)d_in[13];
    const float* b2     = (const float*)d_in[14];
    const float* cb     = (const float*)d_in[15];

    // workspace (<=213 MB; 260 MB proven usable in round 2):
    const size_t SZc = (size_t)25088 * DMODEL;            // floats per slot
    float* wsf = (float*)d_ws;
    float*  S0  = wsf + 0 * SZc;
    float*  S1  = wsf + 1 * SZc;
    float*  S2  = wsf + 2 * SZc;
    float*  S3  = wsf + 3 * SZc;
    float*  Wc  = wsf + 4 * SZc;                          // 2 layers conv weights
    char* p = (char*)(Wc + 2 * 3 * DMODEL * DMODEL);
    double* cbn   = (double*)p;            p += KCB * 8;
    float4* cand  = (float4*)p;            p += (size_t)4 * 12544 * 16;
    int*   idxbuf = (int*)p;               p += 12544 * 4;
    int*   flagbuf= (int*)p;

    k_cbn<<<dim3(KCB), dim3(64), 0, stream>>>(cb, cbn);
    k_wconv<<<dim3(3072), dim3(256), 0, stream>>>(conv_w, Wc);
    k_wconv<<<dim3(3072), dim3(256), 0, stream>>>(conv_w + (size_t)3 * DMODEL * DMODEL,
                                                  Wc + (size_t)3 * DMODEL * DMODEL);

    const float* xin = motion;
    int Tin = 196;
    for (int l = 0; l < 2; l++) {
        int Tout = Tin / 2;            // 98, then 49
        int M = BBATCH * Tout;         // 25088, then 12544
        const float* wq = wqkv + (size_t)l * DMODEL * 3 * DMODEL;
        const float* bq = bqkv + (size_t)l * 3 * DMODEL;
        const float* WcL = Wc + (size_t)l * 3 * DMODEL * DMODEL;

        // conv (fused gather) + GELU: xin -> S0
        k_gemm_conv<<<dim3(DMODEL / 64, M / 64), dim3(256), 0, stream>>>(
            xin, WcL, conv_b + l * DMODEL, S0, Tin, Tout);
        // q,k,v: S0 @ wqkv slices -> S1,S2,S3
        float* qkvdst[3] = {S1, S2, S3};
        for (int s = 0; s < 3; s++) {
            k_gemm<0><<<dim3(DMODEL / 64, M / 64), dim3(256), 0, stream>>>(
                S0, DMODEL, wq + s * DMODEL, 3 * DMODEL, bq + s * DMODEL,
                qkvdst[s], DMODEL, M, DMODEL, DMODEL);
        }
        // attention in-place over q
        k_attn3<<<dim3(Tout, NHEAD, BBATCH), dim3(128), 0, stream>>>(S1, S2, S3, S1, Tout);
        // proj -> S2
        k_gemm<0><<<dim3(DMODEL / 64, M / 64), dim3(256), 0, stream>>>(
            S1, DMODEL, wo + (size_t)l * DMODEL * DMODEL, DMODEL, bo + l * DMODEL,
            S2, DMODEL, M, DMODEL, DMODEL);
        // LN1(S0 + S2) -> S3
        k_ln<<<dim3(M), dim3(128), 0, stream>>>(S0, S2, ln1g + l * DMODEL, ln1b + l * DMODEL, S3);
        // ff1 + ReLU: S3 -> S1 (spans S1..S2 when l=0)
        k_gemm<2><<<dim3(DFFN / 64, M / 64), dim3(256), 0, stream>>>(
            S3, DMODEL, w1 + (size_t)l * DMODEL * DFFN, DFFN, b1 + l * DFFN,
            S1, DFFN, M, DFFN, DMODEL);
        // ff2: S1 -> S0
        k_gemm<0><<<dim3(DMODEL / 64, M / 64), dim3(256), 0, stream>>>(
            S1, DFFN, w2 + (size_t)l * DFFN * DMODEL, DMODEL, b2 + l * DMODEL,
            S0, DMODEL, M, DMODEL, DFFN);
        // LN2(S3 + S0) -> S1 (next x)
        k_ln<<<dim3(M), dim3(128), 0, stream>>>(S3, S0, ln2g + l * DMODEL, ln2b + l * DMODEL, S1);

        xin = S1;
        Tin = Tout;
    }

    // VQ over all 12544 rows (x in S1)
    float* outq = (float*)d_out;
    float* outi = outq + (size_t)12544 * DMODEL;
    k_vq1<<<dim3(12544 / 64, 4), dim3(256), 0, stream>>>(S1, cb, cbn, cand, 12544);
    k_vq2<<<dim3(49), dim3(256), 0, stream>>>(cand, idxbuf, flagbuf, 12544);
    k_vq3<<<dim3(12544), dim3(256), 0, stream>>>(S1, cb, cbn, idxbuf, flagbuf, outq, outi);
}

// Round 6
// 9417.447 us; speedup vs baseline: 2.7957x; 1.5315x over previous
//
#include <hip/hip_runtime.h>
#include <hip/hip_bf16.h>
#include <math.h>

#define BBATCH 256
#define DMODEL 512
#define NHEAD 4
#define DHEAD 128
#define DFFN 1024
#define KCB 8192
#define VEPS 0.02f

// ---------------- conv weight transform: wc[(k*512+di)*512 + do] = cw[do][di][k]
__global__ __launch_bounds__(256) void k_wconv(const float* __restrict__ cw,
                                               float* __restrict__ wc) {
    int idx = blockIdx.x * 256 + threadIdx.x;
    if (idx >= 3 * DMODEL * DMODEL) return;
    int dout = idx & (DMODEL - 1);
    int rest = idx >> 9;
    int di = rest & (DMODEL - 1);
    int k = rest >> 9;
    wc[idx] = cw[((size_t)dout * DMODEL + di) * 3 + k];
}

// ---------------- conv GEMM with fused frame gather + exact GELU, fp64 accumulate.
__global__ __launch_bounds__(256) void k_gemm_conv(const float* __restrict__ xin,
                                                   const float* __restrict__ Wc,
                                                   const float* __restrict__ bias,
                                                   float* __restrict__ C,
                                                   int Tin, int Tout) {
    __shared__ __align__(16) float As[16][68];
    __shared__ __align__(16) float Bs[16][68];
    int tid = threadIdx.x;
    int tx = tid & 15, ty = tid >> 4;
    int m0 = blockIdx.y * 64, n0 = blockIdx.x * 64;
    double acc[4][4];
#pragma unroll
    for (int i = 0; i < 4; i++)
#pragma unroll
        for (int j = 0; j < 4; j++) acc[i][j] = 0.0;

    for (int k0 = 0; k0 < 3 * DMODEL; k0 += 16) {
#pragma unroll
        for (int i = 0; i < 4; i++) {
            int t = tid + i * 256;
            int kk = t & 15, mm = t >> 4;
            int c = k0 + kk;
            int m = m0 + mm;
            int b = m / Tout;
            int tt = m - b * Tout;
            int f = 2 * tt - 2 + (c >> 9);
            if (f < 0) f = 0;
            As[kk][mm] = xin[((size_t)b * Tin + f) * DMODEL + (c & 511)];
            int nn = t & 63, kb = t >> 6;
            Bs[kb][nn] = Wc[(size_t)(k0 + kb) * DMODEL + n0 + nn];
        }
        __syncthreads();
#pragma unroll
        for (int kk = 0; kk < 16; kk++) {
            float4 af = *(const float4*)&As[kk][ty * 4];
            float4 bf = *(const float4*)&Bs[kk][tx * 4];
            double a[4] = {(double)af.x, (double)af.y, (double)af.z, (double)af.w};
            double b[4] = {(double)bf.x, (double)bf.y, (double)bf.z, (double)bf.w};
#pragma unroll
            for (int i = 0; i < 4; i++)
#pragma unroll
                for (int j = 0; j < 4; j++) acc[i][j] = fma(a[i], b[j], acc[i][j]);
        }
        __syncthreads();
    }
#pragma unroll
    for (int i = 0; i < 4; i++) {
#pragma unroll
        for (int j = 0; j < 4; j++) {
            double v = acc[i][j] + (double)bias[n0 + tx * 4 + j];
            v = 0.5 * v * (1.0 + erf(v * 0.7071067811865476));
            C[(size_t)(m0 + ty * 4 + i) * DMODEL + n0 + tx * 4 + j] = (float)v;
        }
    }
}

// ---------------- generic GEMM, fp64 accumulate. ACT: 0 none, 2 relu
template <int ACT>
__global__ __launch_bounds__(256) void k_gemm(const float* __restrict__ A, int lda,
                                              const float* __restrict__ Bm, int ldb,
                                              const float* __restrict__ bias,
                                              float* __restrict__ C, int ldc,
                                              int M, int N, int K) {
    __shared__ __align__(16) float As[16][68];
    __shared__ __align__(16) float Bs[16][68];
    int tid = threadIdx.x;
    int tx = tid & 15, ty = tid >> 4;
    int m0 = blockIdx.y * 64, n0 = blockIdx.x * 64;
    double acc[4][4];
#pragma unroll
    for (int i = 0; i < 4; i++)
#pragma unroll
        for (int j = 0; j < 4; j++) acc[i][j] = 0.0;

    for (int k0 = 0; k0 < K; k0 += 16) {
#pragma unroll
        for (int i = 0; i < 4; i++) {
            int t = tid + i * 256;
            int kk = t & 15, mm = t >> 4;
            As[kk][mm] = A[(size_t)(m0 + mm) * lda + k0 + kk];
            int nn = t & 63, kb = t >> 6;
            Bs[kb][nn] = Bm[(size_t)(k0 + kb) * ldb + n0 + nn];
        }
        __syncthreads();
#pragma unroll
        for (int kk = 0; kk < 16; kk++) {
            float4 af = *(const float4*)&As[kk][ty * 4];
            float4 bf = *(const float4*)&Bs[kk][tx * 4];
            double a[4] = {(double)af.x, (double)af.y, (double)af.z, (double)af.w};
            double b[4] = {(double)bf.x, (double)bf.y, (double)bf.z, (double)bf.w};
#pragma unroll
            for (int i = 0; i < 4; i++)
#pragma unroll
                for (int j = 0; j < 4; j++) acc[i][j] = fma(a[i], b[j], acc[i][j]);
        }
        __syncthreads();
    }
#pragma unroll
    for (int i = 0; i < 4; i++) {
#pragma unroll
        for (int j = 0; j < 4; j++) {
            double v = acc[i][j] + (double)bias[n0 + tx * 4 + j];
            if (ACT == 2) v = v > 0.0 ? v : 0.0;
            C[(size_t)(m0 + ty * 4 + i) * ldc + n0 + tx * 4 + j] = (float)v;
        }
    }
}

// ---------------- attention, separate q,k,v buffers; out may alias q
__global__ __launch_bounds__(128) void k_attn3(const float* q,
                                               const float* __restrict__ k,
                                               const float* __restrict__ v,
                                               float* out, int T) {
    int i = blockIdx.x, h = blockIdx.y, b = blockIdx.z;
    int tid = threadIdx.x;
    __shared__ float qs[DHEAD];
    __shared__ double sc[128];
    __shared__ double red[2];
    size_t rowbase = (size_t)b * T;
    qs[tid] = q[(rowbase + i) * DMODEL + h * DHEAD + tid];
    __syncthreads();
    double sv = -1e300;
    if (tid <= i && tid < T) {
        const float* kr = k + (rowbase + tid) * DMODEL + h * DHEAD;
        double s = 0.0;
#pragma unroll 8
        for (int d = 0; d < DHEAD; d++) s = fma((double)qs[d], (double)kr[d], s);
        sv = s * 0.08838834764831845;
    }
    sc[tid] = sv;
    __syncthreads();
    if (tid == 0) {
        double m = -1e300;
        for (int j = 0; j <= i; j++) m = sc[j] > m ? sc[j] : m;
        red[0] = m;
    }
    __syncthreads();
    double m = red[0];
    if (tid <= i) sc[tid] = exp(sc[tid] - m);
    __syncthreads();
    if (tid == 0) {
        double s = 0.0;
        for (int j = 0; j <= i; j++) s += sc[j];
        red[1] = s;
    }
    __syncthreads();
    double inv = 1.0 / red[1];
    const float* vb = v + rowbase * DMODEL + h * DHEAD + tid;
    double o = 0.0;
    for (int j = 0; j <= i; j++) o = fma(sc[j], (double)vb[(size_t)j * DMODEL], o);
    out[(rowbase + i) * DMODEL + h * DHEAD + tid] = (float)(o * inv);
}

// ---------------- fused residual-add + LayerNorm, one block per row
__global__ __launch_bounds__(128) void k_ln(const float* __restrict__ resid,
                                            const float* __restrict__ y,
                                            const float* __restrict__ g,
                                            const float* __restrict__ bta,
                                            float* __restrict__ out) {
    int row = blockIdx.x;
    int tid = threadIdx.x;
    size_t off = (size_t)row * DMODEL;
    double t[4];
#pragma unroll
    for (int i = 0; i < 4; i++) {
        int d = tid + i * 128;
        t[i] = (double)resid[off + d] + (double)y[off + d];
    }
    __shared__ double rd[2];
    double s = t[0] + t[1] + t[2] + t[3];
#pragma unroll
    for (int o = 32; o > 0; o >>= 1) s += __shfl_down(s, o, 64);
    if ((tid & 63) == 0) rd[tid >> 6] = s;
    __syncthreads();
    double mean = (rd[0] + rd[1]) * (1.0 / 512.0);
    double vs = 0.0;
#pragma unroll
    for (int i = 0; i < 4; i++) { double dl = t[i] - mean; vs += dl * dl; }
    __syncthreads();
#pragma unroll
    for (int o = 32; o > 0; o >>= 1) vs += __shfl_down(vs, o, 64);
    if ((tid & 63) == 0) rd[tid >> 6] = vs;
    __syncthreads();
    double var = (rd[0] + rd[1]) * (1.0 / 512.0);
    double scale = 1.0 / sqrt(var + 1e-5);
#pragma unroll
    for (int i = 0; i < 4; i++) {
        int d = tid + i * 128;
        out[off + d] = (float)((t[i] - mean) * scale * (double)g[d] + (double)bta[d]);
    }
}

// ---------------- codebook squared norms (fp64)
__global__ __launch_bounds__(64) void k_cbn(const float* __restrict__ cb,
                                            double* __restrict__ cbn) {
    int row = blockIdx.x;
    int tid = threadIdx.x;
    const float* r = cb + (size_t)row * DMODEL;
    double s = 0.0;
    for (int d = tid; d < DMODEL; d += 64) { double v = (double)r[d]; s = fma(v, v, s); }
#pragma unroll
    for (int o = 32; o > 0; o >>= 1) s += __shfl_down(s, o, 64);
    if (tid == 0) cbn[row] = s;
}

// ---------------- VQ phase 1: fp32 distances, per-row global top-2 per code-split.
// Grid (nrows/64, 4). 64 rows x 2048 codes per block, GEMM-tiled 64x64x16.
// Conflict-free LDS: both tiles stored [k][idx] with +4 pad, read as float4 (b128).
__global__ __launch_bounds__(256) void k_vq1(const float* __restrict__ x,
                                             const float* __restrict__ cb,
                                             const double* __restrict__ cbn,
                                             float4* __restrict__ cand, int nrows) {
    __shared__ __align__(16) float Xs[16][68];   // [k][row]
    __shared__ __align__(16) float Cs[16][68];   // [k][code]  (transposed at staging)
    __shared__ float sD[64][16][2];
    __shared__ int   sI[64][16][2];
    int tid = threadIdx.x, tx = tid & 15, ty = tid >> 4;
    int r0 = blockIdx.x * 64;
    int cbase = blockIdx.y * 2048;
    float b1[4], b2[4]; int i1[4], i2[4];
#pragma unroll
    for (int i = 0; i < 4; i++) { b1[i] = 1e30f; b2[i] = 1e30f; i1[i] = 0; i2[i] = 0; }

    for (int c0 = cbase; c0 < cbase + 2048; c0 += 64) {
        float acc[4][4];
#pragma unroll
        for (int i = 0; i < 4; i++)
#pragma unroll
            for (int j = 0; j < 4; j++) acc[i][j] = 0.0f;

        for (int k0 = 0; k0 < DMODEL; k0 += 16) {
#pragma unroll
            for (int i = 0; i < 4; i++) {
                int t = tid + i * 256;
                int kk = t & 15, mm = t >> 4;
                Xs[kk][mm] = x[(size_t)(r0 + mm) * DMODEL + k0 + kk];
                Cs[kk][mm] = cb[(size_t)(c0 + mm) * DMODEL + k0 + kk];
            }
            __syncthreads();
#pragma unroll
            for (int kk = 0; kk < 16; kk++) {
                float4 xa = *(const float4*)&Xs[kk][ty * 4];
                float4 ca = *(const float4*)&Cs[kk][tx * 4];
                float xv[4] = {xa.x, xa.y, xa.z, xa.w};
                float cv[4] = {ca.x, ca.y, ca.z, ca.w};
#pragma unroll
                for (int i = 0; i < 4; i++)
#pragma unroll
                    for (int j = 0; j < 4; j++)
                        acc[i][j] = fmaf(xv[i], cv[j], acc[i][j]);
            }
            __syncthreads();
        }
#pragma unroll
        for (int j = 0; j < 4; j++) {
            int ci = c0 + tx * 4 + j;
            float cn = (float)cbn[ci];
#pragma unroll
            for (int i = 0; i < 4; i++) {
                float d = cn - 2.0f * acc[i][j];
                if (d < b1[i]) { b2[i] = b1[i]; i2[i] = i1[i]; b1[i] = d; i1[i] = ci; }
                else if (d < b2[i]) { b2[i] = d; i2[i] = ci; }
            }
        }
    }
#pragma unroll
    for (int i = 0; i < 4; i++) {
        int r = ty * 4 + i;
        sD[r][tx][0] = b1[i]; sD[r][tx][1] = b2[i];
        sI[r][tx][0] = i1[i]; sI[r][tx][1] = i2[i];
    }
    __syncthreads();
    if (tid < 64) {
        float d1 = 1e30f, d2 = 1e30f; int j1 = 0, j2 = 0;
        for (int t = 0; t < 16; t++) {
#pragma unroll
            for (int e = 0; e < 2; e++) {
                float d = sD[tid][t][e]; int ix = sI[tid][t][e];
                if (d < d1 || (d == d1 && ix < j1)) { d2 = d1; j2 = j1; d1 = d; j1 = ix; }
                else if (d < d2 || (d == d2 && ix < j2)) { d2 = d; j2 = ix; }
            }
        }
        cand[(size_t)blockIdx.y * nrows + r0 + tid] =
            make_float4(d1, __int_as_float(j1), d2, __int_as_float(j2));
    }
}

// ---------------- VQ phase 2: merge 4 splits' top-2; flag near-ties for exact rescan
__global__ __launch_bounds__(256) void k_vq2(const float4* __restrict__ cand,
                                             int* __restrict__ idxbuf,
                                             int* __restrict__ flagbuf, int nrows) {
    int row = blockIdx.x * 256 + threadIdx.x;
    if (row >= nrows) return;
    float d1 = 1e30f, d2 = 1e30f; int j1 = 0, j2 = 0;
#pragma unroll
    for (int s = 0; s < 4; s++) {
        float4 c = cand[(size_t)s * nrows + row];
        float dd[2] = {c.x, c.z};
        int ii[2] = {__float_as_int(c.y), __float_as_int(c.w)};
#pragma unroll
        for (int e = 0; e < 2; e++) {
            float d = dd[e]; int ix = ii[e];
            if (d < d1 || (d == d1 && ix < j1)) { d2 = d1; j2 = j1; d1 = d; j1 = ix; }
            else if (d < d2 || (d == d2 && ix < j2)) { d2 = d; j2 = ix; }
        }
    }
    idxbuf[row] = j1;
    flagbuf[row] = (d2 - d1 < VEPS) ? 1 : 0;
}

// ---------------- VQ phase 3: exact fp64 rescan for flagged rows; write outputs
__global__ __launch_bounds__(256) void k_vq3(const float* __restrict__ x,
                                             const float* __restrict__ cb,
                                             const double* __restrict__ cbn,
                                             const int* __restrict__ idxbuf,
                                             const int* __restrict__ flagbuf,
                                             float* __restrict__ outq,
                                             float* __restrict__ outi) {
    int row = blockIdx.x;
    int tid = threadIdx.x;
    int best = idxbuf[row];
    if (flagbuf[row]) {
        __shared__ float xs[DMODEL];
        __shared__ double sd[256];
        __shared__ int si[256];
        xs[tid] = x[(size_t)row * DMODEL + tid];
        xs[tid + 256] = x[(size_t)row * DMODEL + tid + 256];
        __syncthreads();
        double bd = 1e300; int bi = 0x7fffffff;
        for (int c = tid; c < KCB; c += 256) {
            const float* cr = cb + (size_t)c * DMODEL;
            double dot = 0.0;
#pragma unroll 8
            for (int d = 0; d < DMODEL; d++) dot = fma((double)xs[d], (double)cr[d], dot);
            double dist = cbn[c] - 2.0 * dot;
            if (dist < bd || (dist == bd && c < bi)) { bd = dist; bi = c; }
        }
        sd[tid] = bd; si[tid] = bi;
        __syncthreads();
        for (int off = 128; off > 0; off >>= 1) {
            if (tid < off) {
                if (sd[tid + off] < sd[tid] ||
                    (sd[tid + off] == sd[tid] && si[tid + off] < si[tid])) {
                    sd[tid] = sd[tid + off]; si[tid] = si[tid + off];
                }
            }
            __syncthreads();
        }
        best = si[0];
    }
    const float* crow = cb + (size_t)best * DMODEL;
    outq[(size_t)row * DMODEL + tid] = crow[tid];
    outq[(size_t)row * DMODEL + tid + 256] = crow[tid + 256];
    if (tid == 0) outi[row] = (float)best;
}

extern "C" void kernel_launch(void* const* d_in, const int* in_sizes, int n_in,
                              void* d_out, int out_size, void* d_ws, size_t ws_size,
                              hipStream_t stream) {
    const float* motion = (const float*)d_in[0];
    const float* conv_w = (const float*)d_in[1];
    const float* conv_b = (const float*)d_in[2];
    const float* wqkv   = (const float*)d_in[3];
    const float* bqkv   = (const float*)d_in[4];
    const float* wo     = (const float*)d_in[5];
    const float* bo     = (const float*)d_in[6];
    const float* ln1g   = (const float*)d_in[7];
    const float* ln1b   = (const float*)d_in[8];
    const float* ln2g   = (const float*)d_in[9];
    const float* ln2b   = (const float*)d_in[10];
    const float* w1     = (const float*)d_in[11];
    const float* b1     = (const float*)d_in[12];
    const float* w2     = (const float*)d_in[13];
    const float* b2     = (const float*)d_in[14];
    const float* cb     = (const float*)d_in[15];

    const size_t SZc = (size_t)25088 * DMODEL;
    float* wsf = (float*)d_ws;
    float*  S0  = wsf + 0 * SZc;
    float*  S1  = wsf + 1 * SZc;
    float*  S2  = wsf + 2 * SZc;
    float*  S3  = wsf + 3 * SZc;
    float*  Wc  = wsf + 4 * SZc;
    char* p = (char*)(Wc + 2 * 3 * DMODEL * DMODEL);
    double* cbn   = (double*)p;            p += KCB * 8;
    float4* cand  = (float4*)p;            p += (size_t)4 * 12544 * 16;
    int*   idxbuf = (int*)p;               p += 12544 * 4;
    int*   flagbuf= (int*)p;

    k_cbn<<<dim3(KCB), dim3(64), 0, stream>>>(cb, cbn);
    k_wconv<<<dim3(3072), dim3(256), 0, stream>>>(conv_w, Wc);
    k_wconv<<<dim3(3072), dim3(256), 0, stream>>>(conv_w + (size_t)3 * DMODEL * DMODEL,
                                                  Wc + (size_t)3 * DMODEL * DMODEL);

    const float* xin = motion;
    int Tin = 196;
    for (int l = 0; l < 2; l++) {
        int Tout = Tin / 2;            // 98, then 49
        int M = BBATCH * Tout;         // 25088, then 12544
        const float* wq = wqkv + (size_t)l * DMODEL * 3 * DMODEL;
        const float* bq = bqkv + (size_t)l * 3 * DMODEL;
        const float* WcL = Wc + (size_t)l * 3 * DMODEL * DMODEL;

        k_gemm_conv<<<dim3(DMODEL / 64, M / 64), dim3(256), 0, stream>>>(
            xin, WcL, conv_b + l * DMODEL, S0, Tin, Tout);
        float* qkvdst[3] = {S1, S2, S3};
        for (int s = 0; s < 3; s++) {
            k_gemm<0><<<dim3(DMODEL / 64, M / 64), dim3(256), 0, stream>>>(
                S0, DMODEL, wq + s * DMODEL, 3 * DMODEL, bq + s * DMODEL,
                qkvdst[s], DMODEL, M, DMODEL, DMODEL);
        }
        k_attn3<<<dim3(Tout, NHEAD, BBATCH), dim3(128), 0, stream>>>(S1, S2, S3, S1, Tout);
        k_gemm<0><<<dim3(DMODEL / 64, M / 64), dim3(256), 0, stream>>>(
            S1, DMODEL, wo + (size_t)l * DMODEL * DMODEL, DMODEL, bo + l * DMODEL,
            S2, DMODEL, M, DMODEL, DMODEL);
        k_ln<<<dim3(M), dim3(128), 0, stream>>>(S0, S2, ln1g + l * DMODEL, ln1b + l * DMODEL, S3);
        k_gemm<2><<<dim3(DFFN / 64, M / 64), dim3(256), 0, stream>>>(
            S3, DMODEL, w1 + (size_t)l * DMODEL * DFFN, DFFN, b1 + l * DFFN,
            S1, DFFN, M, DFFN, DMODEL);
        k_gemm<0><<<dim3(DMODEL / 64, M / 64), dim3(256), 0, stream>>>(
            S1, DFFN, w2 + (size_t)l * DFFN * DMODEL, DMODEL, b2 + l * DMODEL,
            S0, DMODEL, M, DMODEL, DFFN);
        k_ln<<<dim3(M), dim3(128), 0, stream>>>(S3, S0, ln2g + l * DMODEL, ln2b + l * DMODEL, S1);

        xin = S1;
        Tin = Tout;
    }

    float* outq = (float*)d_out;
    float* outi = outq + (size_t)12544 * DMODEL;
    k_vq1<<<dim3(12544 / 64, 4), dim3(256), 0, stream>>>(S1, cb, cbn, cand, 12544);
    k_vq2<<<dim3(49), dim3(256), 0, stream>>>(cand, idxbuf, flagbuf, 12544);
    k_vq3<<<dim3(12544), dim3(256), 0, stream>>>(S1, cb, cbn, idxbuf, flagbuf, outq, outi);
}